// Round 5
// baseline (299.036 us; speedup 1.0000x reference)
//
#include <hip/hip_runtime.h>

// HairBundleSDE: dx = f(t, x) elementwise over N=8388608 rows x 5 state vars.
// Dtypes (triangulated R0-R4): ALL float32 (t scalar, x N x 5, out N x 5) --
// matching the reference's jnp.float32. The 3.125e-02 threshold is 2% of
// max|ref| (1.5625), not a bf16 floor. R4's 0.2539 error was purely the
// wrong (bf16) decode of t; x/out handling was already correct.
// Traffic: 167.8 MB in + 167.8 MB out = 335.5 MB => ~53us floor @6.3TB/s.
// Each thread: 4 contiguous rows = 20 f32 = 80B in / 80B out (5 x dwordx4 each).

namespace {

constexpr float K_GS      = 0.75f;
constexpr float K_SP      = 0.6f;
constexpr float D0        = 0.5f;
constexpr float DELTA_INV = 5.0f;   // 1/0.2
constexpr float F_MAX     = 1.0f;
constexpr float S_CA      = 0.7f;
constexpr float LAMA_INV  = 0.1f;   // 1/LAM_A
constexpr float AMP       = 0.3f;
constexpr float OMEGA     = 6.283185307179586f;

__device__ __forceinline__ void compute_row(float X, float Xa, float pm, float pgs, float pt,
                                            float force, float* o) {
    float d   = X - Xa;
    float z   = (d - D0) * DELTA_INV;
    float p   = 1.0f / (1.0f + __expf(-z));          // sigmoid((X-Xa-D0)/DELTA)
    float fgs = K_GS * (d - D0 * p);
    o[0] = force - fgs - K_SP * X;                   // dX   (LAM = 1)
    o[1] = (fgs - (F_MAX - S_CA * pm)) * LAMA_INV;   // dXa
    o[2] = 1.5f * p * (1.0f - pm) - pm;              // dpm  (TAU_M = 1)
    o[3] = (1.2f * p * (1.0f - pgs) - pgs) * 0.2f;   // dpgs (TAU_GS = 5)
    o[4] = (0.8f * p * (1.0f - pt)  - pt)  * 0.1f;   // dpt  (TAU_T = 10)
}

} // namespace

__global__ __launch_bounds__(256) void hb_kernel(
        const float* __restrict__ tp,   // f32 scalar
        const float* __restrict__ xp,
        float* __restrict__ op,
        int nrows) {
    const int gid = blockIdx.x * 256 + threadIdx.x;

    // force = AMP * sin(OMEGA * t); t is a single f32 scalar (broadcast load).
    // One precise sinf per thread, cost fully hidden by memory traffic.
    const float force = AMP * sinf(OMEGA * tp[0]);

    const long long row0 = (long long)gid * 4;
    if (row0 + 4 <= (long long)nrows) {
        // ---- fast path: 4 rows = 20 f32 = 80B contiguous, 5 x float4 ----
        const float4* src = reinterpret_cast<const float4*>(xp + row0 * 5);
        float vals[20];
#pragma unroll
        for (int k = 0; k < 5; ++k) {
            float4 v = src[k];
            vals[4*k+0] = v.x; vals[4*k+1] = v.y; vals[4*k+2] = v.z; vals[4*k+3] = v.w;
        }

        float res[20];
#pragma unroll
        for (int r = 0; r < 4; ++r) {
            compute_row(vals[5*r+0], vals[5*r+1], vals[5*r+2], vals[5*r+3], vals[5*r+4],
                        force, &res[5*r]);
        }

        float4* dst = reinterpret_cast<float4*>(op + row0 * 5);
#pragma unroll
        for (int k = 0; k < 5; ++k)
            dst[k] = make_float4(res[4*k+0], res[4*k+1], res[4*k+2], res[4*k+3]);
    } else {
        // ---- tail path (not taken for N=8388608, kept for robustness) ----
        for (long long r = row0; r < (long long)nrows; ++r) {
            float in[5], out[5];
            for (int j = 0; j < 5; ++j) in[j] = xp[r*5 + j];
            compute_row(in[0], in[1], in[2], in[3], in[4], force, out);
            for (int j = 0; j < 5; ++j) op[r*5 + j] = out[j];
        }
    }
}

extern "C" void kernel_launch(void* const* d_in, const int* in_sizes, int n_in,
                              void* d_out, int out_size, void* d_ws, size_t ws_size,
                              hipStream_t stream) {
    const float* t = (const float*)d_in[0];
    const float* x = (const float*)d_in[1];
    float* out     = (float*)d_out;

    const long long nrows    = (long long)in_sizes[1] / 5;     // 8388608
    const long long nthreads = (nrows + 3) / 4;
    const int grid = (int)((nthreads + 255) / 256);            // 8192 blocks

    hb_kernel<<<grid, 256, 0, stream>>>(t, x, out, (int)nrows);
}

// Round 6
// 282.820 us; speedup vs baseline: 1.0573x; 1.0573x over previous
//
#include <hip/hip_runtime.h>

// HairBundleSDE: dx = f(t, x) elementwise, N=8388608 rows x 5 f32 state vars.
// All tensors f32 (t scalar, x N x 5, out N x 5). R5 passed at 109us/dispatch
// = 3.08 TB/s logical (30% peak): limiter was the 80B-lane-stride dwordx4
// pattern (each wave op scatters 64x16B over ~80 cache lines -> request-rate
// bound, not byte bound; FETCH/WRITE were already ideal, VALUBusy 8.9%).
// Fix: all global accesses lane-consecutive float4; row gather/scatter goes
// through LDS. LDS row stride = 20 floats: lane-stride 20 mod 32 banks means
// each 8-lane group tiles all 32 banks exactly once -> conflict-free.
// Block = 256 threads <-> 1024 rows (20KB). Two 20KB LDS buffers, 2 barriers.
// Grid = 8192 blocks (exactly N/1024). Traffic 335.5MB logical => ~53us floor.

namespace {

constexpr float K_GS      = 0.75f;
constexpr float K_SP      = 0.6f;
constexpr float D0        = 0.5f;
constexpr float DELTA_INV = 5.0f;   // 1/0.2
constexpr float F_MAX     = 1.0f;
constexpr float S_CA      = 0.7f;
constexpr float LAMA_INV  = 0.1f;   // 1/LAM_A
constexpr float AMP       = 0.3f;
constexpr float OMEGA     = 6.283185307179586f;

constexpr int BLOCK       = 256;
constexpr int ROWS_PER_T  = 4;
constexpr int CHUNK_ROWS  = BLOCK * ROWS_PER_T;          // 1024
constexpr int CHUNK_F4    = CHUNK_ROWS * 5 / 4;          // 1280 float4 = 20KB

__device__ __forceinline__ void compute_row(float X, float Xa, float pm, float pgs, float pt,
                                            float force, float* o) {
    float d   = X - Xa;
    float z   = (d - D0) * DELTA_INV;
    float p   = 1.0f / (1.0f + __expf(-z));          // sigmoid((X-Xa-D0)/DELTA)
    float fgs = K_GS * (d - D0 * p);
    o[0] = force - fgs - K_SP * X;                   // dX   (LAM = 1)
    o[1] = (fgs - (F_MAX - S_CA * pm)) * LAMA_INV;   // dXa
    o[2] = 1.5f * p * (1.0f - pm) - pm;              // dpm  (TAU_M = 1)
    o[3] = (1.2f * p * (1.0f - pgs) - pgs) * 0.2f;   // dpgs (TAU_GS = 5)
    o[4] = (0.8f * p * (1.0f - pt)  - pt)  * 0.1f;   // dpt  (TAU_T = 10)
}

} // namespace

__global__ __launch_bounds__(BLOCK) void hb_kernel(
        const float* __restrict__ tp,
        const float* __restrict__ xp,
        float* __restrict__ op,
        long long nrows) {
    __shared__ float4 sIn[CHUNK_F4];    // 20 KB
    __shared__ float4 sOut[CHUNK_F4];   // 20 KB

    const int tid = threadIdx.x;
    const long long chunk0 = (long long)blockIdx.x * CHUNK_ROWS;

    // force = AMP * sin(OMEGA * t); one precise sinf per thread, fully hidden.
    const float force = AMP * sinf(OMEGA * tp[0]);

    if (chunk0 + CHUNK_ROWS <= nrows) {
        // ---- stage 1: coalesced global -> LDS (lane-consecutive float4) ----
        const float4* gsrc = reinterpret_cast<const float4*>(xp + chunk0 * 5);
#pragma unroll
        for (int k = 0; k < 5; ++k)
            sIn[tid + BLOCK * k] = gsrc[tid + BLOCK * k];
        __syncthreads();

        // ---- stage 2: row-gather from LDS (80B/thread, bank-conflict-free),
        //               compute, row-scatter results into sOut ----
        const float4* rsrc = reinterpret_cast<const float4*>(
                                 reinterpret_cast<const float*>(sIn) + tid * 20);
        float vals[20];
#pragma unroll
        for (int k = 0; k < 5; ++k) {
            float4 v = rsrc[k];
            vals[4*k+0] = v.x; vals[4*k+1] = v.y; vals[4*k+2] = v.z; vals[4*k+3] = v.w;
        }

        float res[20];
#pragma unroll
        for (int r = 0; r < ROWS_PER_T; ++r)
            compute_row(vals[5*r+0], vals[5*r+1], vals[5*r+2], vals[5*r+3], vals[5*r+4],
                        force, &res[5*r]);

        float4* rdst = reinterpret_cast<float4*>(
                           reinterpret_cast<float*>(sOut) + tid * 20);
#pragma unroll
        for (int k = 0; k < 5; ++k)
            rdst[k] = make_float4(res[4*k+0], res[4*k+1], res[4*k+2], res[4*k+3]);
        __syncthreads();

        // ---- stage 3: coalesced LDS -> global ----
        float4* gdst = reinterpret_cast<float4*>(op + chunk0 * 5);
#pragma unroll
        for (int k = 0; k < 5; ++k)
            gdst[tid + BLOCK * k] = sOut[tid + BLOCK * k];
    } else {
        // ---- tail path (not taken for N=8388608, kept for robustness) ----
        for (long long r = chunk0 + tid * ROWS_PER_T;
             r < nrows && r < chunk0 + (long long)(tid + 1) * ROWS_PER_T; ++r) {
            float in[5], out[5];
            for (int j = 0; j < 5; ++j) in[j] = xp[r*5 + j];
            compute_row(in[0], in[1], in[2], in[3], in[4], force, out);
            for (int j = 0; j < 5; ++j) op[r*5 + j] = out[j];
        }
    }
}

extern "C" void kernel_launch(void* const* d_in, const int* in_sizes, int n_in,
                              void* d_out, int out_size, void* d_ws, size_t ws_size,
                              hipStream_t stream) {
    const float* t = (const float*)d_in[0];
    const float* x = (const float*)d_in[1];
    float* out     = (float*)d_out;

    const long long nrows = (long long)in_sizes[1] / 5;            // 8388608
    const int grid = (int)((nrows + CHUNK_ROWS - 1) / CHUNK_ROWS); // 8192

    hb_kernel<<<grid, BLOCK, 0, stream>>>(t, x, out, nrows);
}